// Round 7
// baseline (27360.568 us; speedup 1.0000x reference)
//
#include <hip/hip_runtime.h>
#include <hip/hip_bf16.h>
#include <hip/hip_cooperative_groups.h>

namespace cg = cooperative_groups;

typedef __bf16 bf16;
typedef __bf16 bf16x8 __attribute__((ext_vector_type(8)));
typedef float  floatx4 __attribute__((ext_vector_type(4)));
typedef unsigned int uint32;

#define NB   64      // batch
#define NT   240     // timesteps
#define NDIM 512     // audio feature dim
#define NU   1024    // LSTM units
#define NOUT 75      // motion dim
#define NWG  64
#define NTHR 1024

// ring slot strides (elements)
#define HSLOT (64 * 1024)
#define YW    80
#define YSLOT (64 * YW)
#define BW    528
#define BSLOT (64 * BW)

struct Params {
  const float* curr;      // [64,75]
  const float* bias[8];   // enc1,enc2,enc3,fc,dec1,dec2,dec3,out
  const bf16*  pk[8];     // packed weights (B-fragment layout)
  const bf16*  audio_bf;  // [64, 240*512] bf16
  bf16* hr[6];            // h rings [R][64][1024] (enc1..3, dec1..3)
  bf16* ybuf;             // [R][64][80]  (y feedback, cols 75..79 zero)
  bf16* hbot;             // [R][64][528] (_h bottleneck, cols 512..527 zeroed)
  uint32* arrv;           // [64*32] arrival flags (128B spaced)
  uint32* gof;            // (unused, kept for layout)
  float* out;             // [64,240,75]
  int rmask;              // ring depth - 1
  int pmask;              // heavy-sync period - 1
};

__device__ __forceinline__ float sigmoidf_(float x) { return 1.f / (1.f + __expf(-x)); }

// ---- single-hop grid barrier ----
// Every WG posts its own flag line; wave 0's 64 lanes each poll one distinct
// 128B line. One L3 round-trip (store-visible -> poll-hit) instead of the
// two-hop gather+broadcast. Mechanism proven in the round-2 p2p variant.
__device__ __forceinline__ void gbar(uint32* arrv, uint32 sc, int w, int tid)
{
  asm volatile("s_waitcnt vmcnt(0)" ::: "memory");
  __syncthreads();
  if (tid == 0)
    __hip_atomic_store(&arrv[w * 32], sc, __ATOMIC_RELAXED, __HIP_MEMORY_SCOPE_AGENT);
  if (tid < NWG) {
    int spin = 0;
    while (__hip_atomic_load(&arrv[tid * 32], __ATOMIC_RELAXED, __HIP_MEMORY_SCOPE_AGENT) < sc) {
      __builtin_amdgcn_s_sleep(1);
      if (++spin > (1 << 24)) break;  // bail instead of hard hang
    }
  }
  __syncthreads();
}

// One LSTM cell stage, DMA-pipelined.
// A = [p0 (B1) | p1 (B2-B1) | p2 (KTOT-B2)], widths mult of 8. WG w owns units
// [16w,16w+16). 16 waves = 4 gates (g=wid&3) x 4 M-splits (v=wid>>2, full K).
// K in chunks of 128 (4 k-blocks): A-subtile 16KB + B-subtile 16KB staged via
// global_load_lds (32 x 1KB, 2 per wave), QUAD-buffered, 3 chunks in flight,
// counted s_waitcnt vmcnt + raw s_barrier (NOT __syncthreads - would drain
// vmcnt and kill the prefetch pipeline). c-state lives in a per-thread reg.
template<int ST0, int B1, int ST1, int B2, int ST2, int KTOT, int KREAL>
__device__ void lstm_cell(const bf16* __restrict__ p0, const bf16* __restrict__ p1,
                          const bf16* __restrict__ p2,
                          const bf16* __restrict__ pack, const float* __restrict__ bias,
                          bf16* __restrict__ hout, float& ccr,
                          float (* __restrict__ zbuf)[64][16], bf16 (* __restrict__ hstage)[16],
                          char* __restrict__ cb0, char* __restrict__ cb1,
                          char* __restrict__ cb2, char* __restrict__ cb3,
                          int w, int tid)
{
  const int lane = tid & 63, wid = tid >> 6;
  const int g = wid & 3, v = wid >> 2;
  const int lq = lane >> 4, lr = lane & 15;
  constexpr int NCH = KTOT / 128;   // >= 12 for all lstm stages

  // ---- DMA issue: 2 instructions per wave per chunk (32 total: 16 A + 16 B) ----
  // chunk LDS layout: [A: kb(4) x mt(4) x 1KB][B: kb(4) x gate(4) x 1KB]
  auto issue = [&](int J, char* bufp) {
    #pragma unroll
    for (int ii = 0; ii < 2; ++ii) {
      const int idx = 2 * wid + ii;          // 0..31, wave-uniform
      const int kb  = (idx >> 2) & 3;
      const int sel = idx & 3;
      if (idx < 16) {                        // A: rows 16*sel+lr, k = J*128+kb*32+lq*8
        int kq = J * 128 + kb * 32 + lq * 8;
        if constexpr (KREAL < KTOT) { if (kq >= KREAL) kq = B2; }   // tail: safe addr x 0-weight
        const int row = 16 * sel + lr;
        const bf16* src;
        if (kq < B1)      src = p0 + (size_t)row * ST0 + kq;
        else if (kq < B2) src = p1 + (size_t)row * ST1 + (kq - B1);
        else              src = p2 + (size_t)row * ST2 + (kq - B2);
        __builtin_amdgcn_global_load_lds((const uint32*)src,
            (uint32*)(bufp + (kb * 4 + sel) * 1024), 16, 0, 0);
      } else {                               // B: cols 1024*sel + 16w + lr, kq8 = J*16+kb*4+lq
        const int kq8 = J * 16 + kb * 4 + lq;
        const bf16* src = pack + ((size_t)kq8 * 4096 + 1024 * sel + 16 * w + lr) * 8;
        __builtin_amdgcn_global_load_lds((const uint32*)src,
            (uint32*)(bufp + 16384 + (kb * 4 + sel) * 1024), 16, 0, 0);
      }
    }
  };

  floatx4 c = {0.f, 0.f, 0.f, 0.f};
  auto compute = [&](const char* bufp) {
    #pragma unroll
    for (int kb = 0; kb < 4; ++kb) {
      bf16x8 af  = *(const bf16x8*)(bufp + (kb * 4 + v) * 1024 + lane * 16);
      bf16x8 bfr = *(const bf16x8*)(bufp + 16384 + (kb * 4 + g) * 1024 + lane * 16);
      c = __builtin_amdgcn_mfma_f32_16x16x32_bf16(af, bfr, c, 0, 0, 0);
    }
  };

  // entered post-gbar: vmcnt==0, all waves past prior LDS use
  char *pA = cb0, *pB = cb1, *pC = cb2, *pD = cb3;
  issue(0, pA);
  issue(1, pB);
  issue(2, pC);
  // steady rounds: chunk J consumed while J+1, J+2 in flight; issue J+3
  for (int J = 0; J + 3 < NCH; ++J) {
    asm volatile("s_waitcnt vmcnt(4)" ::: "memory");   // own 2 loads of chunk J done
    __builtin_amdgcn_s_barrier();                       // => ALL waves' chunk-J parts done
    asm volatile("" ::: "memory");
    issue(J + 3, pD);                                   // pD computed at round J-1: free
    compute(pA);
    char* t = pA; pA = pB; pB = pC; pC = pD; pD = t;
  }
  // tail: chunks NCH-3, NCH-2, NCH-1 (outstanding 6 -> 4 -> 2 loads)
  asm volatile("s_waitcnt vmcnt(4)" ::: "memory");
  __builtin_amdgcn_s_barrier();
  asm volatile("" ::: "memory");
  compute(pA);
  { char* t = pA; pA = pB; pB = pC; pC = pD; pD = t; }
  asm volatile("s_waitcnt vmcnt(2)" ::: "memory");
  __builtin_amdgcn_s_barrier();
  asm volatile("" ::: "memory");
  compute(pA);
  { char* t = pA; pA = pB; pB = pC; pC = pD; pD = t; }
  asm volatile("s_waitcnt vmcnt(0)" ::: "memory");
  __builtin_amdgcn_s_barrier();
  asm volatile("" ::: "memory");
  compute(pA);

  // z -> zbuf: wave (g,v) owns rows 16v + lq*4 + r, col lr (full-K, no reduce)
  #pragma unroll
  for (int r = 0; r < 4; ++r)
    zbuf[g][16 * v + lq * 4 + r][lr] = c[r];
  __syncthreads();
  // pointwise: 1024 threads = 64 rows x 16 units; c-state in per-thread reg
  {
    const int m = tid >> 4, u = tid & 15;
    const int uc = 16 * w + u;
    const float zi = zbuf[0][m][u] + bias[uc];
    const float zf = zbuf[1][m][u] + bias[NU + uc];
    const float zg = zbuf[2][m][u] + bias[2 * NU + uc];
    const float zo = zbuf[3][m][u] + bias[3 * NU + uc];
    const float cold = ccr;
    const float cn = sigmoidf_(zf) * cold + sigmoidf_(zi) * tanhf(zg);
    ccr = cn;
    hstage[m][u] = (bf16)(sigmoidf_(zo) * tanhf(cn));
  }
  __syncthreads();
  // agent-scope (write-through) dword stores so other XCDs see fresh data
  if (tid < 512) {
    const int m = tid >> 3, up = tid & 7;
    const uint32 vv = *(const uint32*)&hstage[m][2 * up];
    __hip_atomic_store((uint32*)(hout + (size_t)m * NU + 16 * w) + up, vv,
                       __ATOMIC_RELAXED, __HIP_MEMORY_SCOPE_AGENT);
  }
}

// Small GEMM (fc / out): z[64,NEFF] = A[64,1024] @ pack. 16 waves: v=wid&3 rows, s=wid>>2 K.
// 8 k-blocks/wave: weights preloaded, A 2-deep pipelined (small enough for regs).
template<int NEFF>
__device__ void gemm_small(const bf16* __restrict__ a, const bf16* __restrict__ pack,
                           float (* __restrict__ zbuf)[64][16], int w, int tid)
{
  const int lane = tid & 63, wid = tid >> 6;
  const int v = wid & 3, s = wid >> 2;
  const int lr = lane & 15, lq = lane >> 4;
  const int n0 = 16 * w;

  const bf16* wbase = pack + ((size_t)lq * NEFF + (n0 + lr)) * 8;

  bf16x8 wreg[8];
  #pragma unroll
  for (int i = 0; i < 8; ++i)
    wreg[i] = *(const bf16x8*)(wbase + (size_t)(s + 4 * i) * (4 * NEFF * 8));

  floatx4 c = {0.f,0.f,0.f,0.f};
  const bf16* ab = a + (size_t)(16 * v + lr) * NU;

  bf16x8 xa[2];
  xa[0] = *(const bf16x8*)(ab + s * 32 + lq * 8);
  #pragma unroll
  for (int i = 0; i < 8; ++i) {
    const int cur = i & 1, nxt = cur ^ 1;
    if (i + 1 < 8)
      xa[nxt] = *(const bf16x8*)(ab + (s + 4 * (i + 1)) * 32 + lq * 8);
    c = __builtin_amdgcn_mfma_f32_16x16x32_bf16(xa[cur], wreg[i], c, 0, 0, 0);
  }

  #pragma unroll
  for (int r = 0; r < 4; ++r) zbuf[s][16 * v + lq * 4 + r][lr] = c[r];
  __syncthreads();
}

extern "C" __global__ void __launch_bounds__(NTHR)
dancer_main(Params p)
{
  __shared__ __align__(16) char cbuf[4][32768];  // 128 KB DMA chunk buffers (A 16K + B 16K)
  __shared__ float zbuf[4][64][16];              // 16 KB gate exchange
  __shared__ bf16  hstage[64][16];               // 2 KB h staging
  cg::grid_group grid = cg::this_grid();
  const int tid = threadIdx.x;
  const int w = blockIdx.x;
  const int gtid = w * NTHR + tid;
  const int rmask = p.rmask, pmask = p.pmask;

  // per-thread c-state for the 6 LSTM layers (tid -> (m,u) fixed mapping)
  float cc0 = 0.f, cc1 = 0.f, cc2 = 0.f, cc3 = 0.f, cc4 = 0.f, cc5 = 0.f;

  // ---- init: zero flags, zero h ring slot 'rmask', ybuf slot 0 from curr,
  //      zero hbot junk cols (512..527, all slots) ----
  if (tid == 0) {
    p.arrv[w * 32] = 0;
    if (w == 0) *p.gof = 0;
  }
  for (int i = gtid; i < 6 * NB * NU; i += NWG * NTHR) {
    const int b = i >> 16, off = i & 65535;
    p.hr[b][(size_t)rmask * HSLOT + off] = (bf16)0.f;
  }
  for (int i = gtid; i < NB * YW; i += NWG * NTHR) {
    const int m = i / YW, c = i - m * YW;
    p.ybuf[i] = (c < NOUT) ? (bf16)p.curr[m * NOUT + c] : (bf16)0.f;
  }
  for (int i = gtid; i < (rmask + 1) * NB * 16; i += NWG * NTHR) {
    const int slot = i >> 10, m = (i >> 4) & 63, cix = i & 15;
    p.hbot[(size_t)slot * BSLOT + (size_t)m * BW + 512 + cix] = (bf16)0.f;
  }
  __syncthreads();
  grid.sync();   // full fence once: init writes visible everywhere

  uint32 sc = 1;
  for (int t = 0; t < NT; ++t) {
    const int st_ = t & rmask;
    const int sp_ = (t - 1) & rmask;
    __syncthreads();  // protect zbuf/hstage/cbuf reuse against previous readers

    // enc1: A = [audio_t (512) | h_enc1(t-1) (1024)], K=1536 (12 chunks)
    lstm_cell<NT * NDIM, NDIM, NU, NDIM, NU, NDIM + NU, NDIM + NU>(
        p.audio_bf + t * NDIM, p.hr[0] + (size_t)sp_ * HSLOT, p.hr[0] + (size_t)sp_ * HSLOT,
        p.pk[0], p.bias[0], p.hr[0] + (size_t)st_ * HSLOT, cc0, zbuf, &hstage[0],
        cbuf[0], cbuf[1], cbuf[2], cbuf[3], w, tid);
    gbar(p.arrv, sc++, w, tid);

    lstm_cell<NU, NU, NU, NU, NU, 2 * NU, 2 * NU>(
        p.hr[0] + (size_t)st_ * HSLOT, p.hr[1] + (size_t)sp_ * HSLOT, p.hr[1] + (size_t)sp_ * HSLOT,
        p.pk[1], p.bias[1], p.hr[1] + (size_t)st_ * HSLOT, cc1, zbuf, &hstage[0],
        cbuf[0], cbuf[1], cbuf[2], cbuf[3], w, tid);
    gbar(p.arrv, sc++, w, tid);

    lstm_cell<NU, NU, NU, NU, NU, 2 * NU, 2 * NU>(
        p.hr[1] + (size_t)st_ * HSLOT, p.hr[2] + (size_t)sp_ * HSLOT, p.hr[2] + (size_t)sp_ * HSLOT,
        p.pk[2], p.bias[2], p.hr[2] + (size_t)st_ * HSLOT, cc2, zbuf, &hstage[0],
        cbuf[0], cbuf[1], cbuf[2], cbuf[3], w, tid);
    gbar(p.arrv, sc++, w, tid);

    // fc: _h = tanh(h_enc3 @ fc_W + b) -> hbot slot t
    if (w < 32) {
      gemm_small<512>(p.hr[2] + (size_t)st_ * HSLOT, p.pk[3], zbuf, w, tid);
      const int m = tid >> 4, u = tid & 15;
      const float z = zbuf[0][m][u] + zbuf[1][m][u] + zbuf[2][m][u] + zbuf[3][m][u]
                      + p.bias[3][16 * w + u];
      hstage[m][u] = (bf16)tanhf(z);
      __syncthreads();
      if (tid < 512) {
        const int m2 = tid >> 3, up = tid & 7;
        const uint32 v = *(const uint32*)&hstage[m2][2 * up];
        __hip_atomic_store((uint32*)(p.hbot + (size_t)st_ * BSLOT + (size_t)m2 * BW + 16 * w) + up,
                           v, __ATOMIC_RELAXED, __HIP_MEMORY_SCOPE_AGENT);
      }
    }
    gbar(p.arrv, sc++, w, tid);

    // dec1: A = [ybuf(t) (80) | hbot(t) (528) | h_dec1(t-1) (1024)],
    // K padded 1632->1664 (13 chunks); tail A clamped, tail B zero-packed
    lstm_cell<YW, YW, BW, YW + BW, NU, 1664, YW + BW + NU>(
        p.ybuf + (size_t)st_ * YSLOT, p.hbot + (size_t)st_ * BSLOT, p.hr[3] + (size_t)sp_ * HSLOT,
        p.pk[4], p.bias[4], p.hr[3] + (size_t)st_ * HSLOT, cc3, zbuf, &hstage[0],
        cbuf[0], cbuf[1], cbuf[2], cbuf[3], w, tid);
    gbar(p.arrv, sc++, w, tid);

    lstm_cell<NU, NU, NU, NU, NU, 2 * NU, 2 * NU>(
        p.hr[3] + (size_t)st_ * HSLOT, p.hr[4] + (size_t)sp_ * HSLOT, p.hr[4] + (size_t)sp_ * HSLOT,
        p.pk[5], p.bias[5], p.hr[4] + (size_t)st_ * HSLOT, cc4, zbuf, &hstage[0],
        cbuf[0], cbuf[1], cbuf[2], cbuf[3], w, tid);
    gbar(p.arrv, sc++, w, tid);

    lstm_cell<NU, NU, NU, NU, NU, 2 * NU, 2 * NU>(
        p.hr[4] + (size_t)st_ * HSLOT, p.hr[5] + (size_t)sp_ * HSLOT, p.hr[5] + (size_t)sp_ * HSLOT,
        p.pk[6], p.bias[6], p.hr[5] + (size_t)st_ * HSLOT, cc5, zbuf, &hstage[0],
        cbuf[0], cbuf[1], cbuf[2], cbuf[3], w, tid);
    gbar(p.arrv, sc++, w, tid);

    // out: y = elu(h_dec3 @ out_W + b) -> d_out and ybuf slot t+1 (no barrier:
    // covered by next step's chain before dec1 reads it)
    if (w < 5) {
      gemm_small<80>(p.hr[5] + (size_t)st_ * HSLOT, p.pk[7], zbuf, w, tid);
      const int m = tid >> 4, u = tid & 15;
      const int n = 16 * w + u;
      float y = 0.f;
      if (n < NOUT) {
        const float z = zbuf[0][m][u] + zbuf[1][m][u] + zbuf[2][m][u] + zbuf[3][m][u]
                        + p.bias[7][n];
        y = (z > 0.f) ? z : (__expf(z) - 1.f);
        p.out[(m * NT + t) * NOUT + n] = y;
      }
      hstage[m][u] = (bf16)y;
      __syncthreads();
      if (tid < 512) {
        const int m2 = tid >> 3, up = tid & 7;
        const uint32 v = *(const uint32*)&hstage[m2][2 * up];
        const size_t sn = (size_t)((t + 1) & rmask) * YSLOT;
        __hip_atomic_store((uint32*)(p.ybuf + sn + (size_t)m2 * YW + 16 * w) + up,
                           v, __ATOMIC_RELAXED, __HIP_MEMORY_SCOPE_AGENT);
      }
    }
    // periodic full sync: flush any cached ring lines before slot reuse
    if ((t & pmask) == pmask) grid.sync();
  }
}

// ---- pre-kernels ----

__global__ void pack_w(const float* __restrict__ Wx, const float* __restrict__ Wh,
                       int Kx, int KhStart, int Keff, int N, int Neff,
                       bf16* __restrict__ dst)
{
  const int idx = blockIdx.x * blockDim.x + threadIdx.x;
  const int nkb = Keff >> 3;
  const int total = nkb * Neff;
  if (idx >= total) return;
  const int kb = idx / Neff;
  const int n  = idx - kb * Neff;
  bf16x8 o;
  #pragma unroll
  for (int j = 0; j < 8; ++j) {
    const int k = kb * 8 + j;
    float v = 0.f;
    if (n < N) {
      if (k < Kx) v = Wx[(size_t)k * N + n];
      else if (k >= KhStart) v = Wh[(size_t)(k - KhStart) * N + n];
    }
    o[j] = (bf16)v;
  }
  *(bf16x8*)(dst + ((size_t)kb * Neff + n) * 8) = o;
}

// dec1: rows 0..74 = Wx[0..74] (y), 75..79 = 0, 80..591 = Wx[75..586] (_h),
//       592..607 = 0, 608..1631 = Wh, 1632..1663 = 0 (chunk pad). K=1664, N=4096.
__global__ void pack_dec1(const float* __restrict__ Wx, const float* __restrict__ Wh,
                          bf16* __restrict__ dst)
{
  const int idx = blockIdx.x * blockDim.x + threadIdx.x;
  const int total = (1664 >> 3) * 4096;
  if (idx >= total) return;
  const int kb = idx >> 12;
  const int n  = idx & 4095;
  bf16x8 o;
  #pragma unroll
  for (int j = 0; j < 8; ++j) {
    const int k = kb * 8 + j;
    float v = 0.f;
    if (k < 75)                    v = Wx[(size_t)k * 4096 + n];
    else if (k >= 80 && k < 592)   v = Wx[(size_t)(k - 5) * 4096 + n];
    else if (k >= 608 && k < 1632) v = Wh[(size_t)(k - 608) * 4096 + n];
    o[j] = (bf16)v;
  }
  *(bf16x8*)(dst + ((size_t)kb * 4096 + n) * 8) = o;
}

__global__ void cvt_bf16(const float* __restrict__ src, bf16* __restrict__ dst, int n)
{
  const int i = blockIdx.x * blockDim.x + threadIdx.x;
  if (i < n) dst[i] = (bf16)src[i];
}

extern "C" void kernel_launch(void* const* d_in, const int* in_sizes, int n_in,
                              void* d_out, int out_size, void* d_ws, size_t ws_size,
                              hipStream_t stream)
{
  (void)in_sizes; (void)n_in; (void)out_size;

  const float* audio = (const float*)d_in[0];
  const float* curr  = (const float*)d_in[1];
  const float* Wp[8][2] = {
    { (const float*)d_in[2],  (const float*)d_in[3]  },  // enc1
    { (const float*)d_in[5],  (const float*)d_in[6]  },  // enc2
    { (const float*)d_in[8],  (const float*)d_in[9]  },  // enc3
    { (const float*)d_in[11], nullptr                },  // fc
    { (const float*)d_in[13], (const float*)d_in[14] },  // dec1
    { (const float*)d_in[16], (const float*)d_in[17] },  // dec2
    { (const float*)d_in[19], (const float*)d_in[20] },  // dec3
    { (const float*)d_in[22], nullptr                },  // out
  };
  const float* bias[8] = {
    (const float*)d_in[4],  (const float*)d_in[7],  (const float*)d_in[10],
    (const float*)d_in[12], (const float*)d_in[15], (const float*)d_in[18],
    (const float*)d_in[21], (const float*)d_in[23],
  };

  // {Kx, KhStart, Keff, N, Neff}; dec1 handled by pack_dec1 (K padded to 1664)
  const int geo[8][5] = {
    { 512,  512,  1536, 4096, 4096 },  // enc1
    { 1024, 1024, 2048, 4096, 4096 },  // enc2
    { 1024, 1024, 2048, 4096, 4096 },  // enc3
    { 1024, 1024, 1024, 512,  512  },  // fc
    { 0,    0,    1664, 4096, 4096 },  // dec1 (custom, padded)
    { 1024, 1024, 2048, 4096, 4096 },  // dec2
    { 1024, 1024, 2048, 4096, 4096 },  // dec3
    { 1024, 1024, 1024, 75,   80   },  // out
  };

  char* ws = (char*)d_ws;
  size_t off = 0;
  auto take = [&](size_t bytes) -> char* {
    char* p = ws + off;
    off = (off + bytes + 255) & ~(size_t)255;
    return p;
  };

  bf16* audio_bf = (bf16*)take((size_t)NB * NT * NDIM * 2);
  bf16* pk[8];
  for (int i = 0; i < 8; ++i) pk[i] = (bf16*)take((size_t)geo[i][2] * geo[i][4] * 2);
  uint32* arrv = (uint32*)take(64 * 32 * sizeof(uint32));
  uint32* gof  = (uint32*)take(256);

  // pick ring depth that fits ws
  const size_t slot_bytes = (size_t)6 * HSLOT * 2 + (size_t)YSLOT * 2 + (size_t)BSLOT * 2 + 4096;
  int R = 32;
  while (R > 4 && off + (size_t)R * slot_bytes + (1 << 20) > ws_size) R >>= 1;

  bf16* hr[6];
  for (int i = 0; i < 6; ++i) hr[i] = (bf16*)take((size_t)R * HSLOT * 2);
  bf16* ybuf = (bf16*)take((size_t)R * YSLOT * 2);
  bf16* hbot = (bf16*)take((size_t)R * BSLOT * 2);

  {
    const int n = NB * NT * NDIM;
    cvt_bf16<<<(n + 255) / 256, 256, 0, stream>>>(audio, audio_bf, n);
  }
  for (int i = 0; i < 8; ++i) {
    if (i == 4) {
      const int total = (1664 >> 3) * 4096;
      pack_dec1<<<(total + 255) / 256, 256, 0, stream>>>(Wp[4][0], Wp[4][1], pk[4]);
    } else {
      const int total = (geo[i][2] >> 3) * geo[i][4];
      pack_w<<<(total + 255) / 256, 256, 0, stream>>>(
          Wp[i][0], Wp[i][1], geo[i][0], geo[i][1], geo[i][2], geo[i][3], geo[i][4], pk[i]);
    }
  }

  Params P;
  P.curr = curr;
  for (int i = 0; i < 8; ++i) { P.bias[i] = bias[i]; P.pk[i] = pk[i]; }
  P.audio_bf = audio_bf;
  for (int i = 0; i < 6; ++i) P.hr[i] = hr[i];
  P.ybuf = ybuf;
  P.hbot = hbot;
  P.arrv = arrv;
  P.gof = gof;
  P.out = (float*)d_out;
  P.rmask = R - 1;
  P.pmask = (R >> 1) - 1;

  void* args[] = { &P };
  (void)hipLaunchCooperativeKernel(reinterpret_cast<void*>(dancer_main),
                                   dim3(NWG), dim3(NTHR), args, 0, stream);
}